// Round 5
// baseline (277.712 us; speedup 1.0000x reference)
//
#include <hip/hip_runtime.h>
#include <math.h>

#define DD 256
#define GG 2048
#define CAP 128   // LDS-cached rows per graph (bf16)

typedef __attribute__((ext_vector_type(8))) short short8;
typedef __attribute__((ext_vector_type(4))) float f32x4;

__device__ __forceinline__ unsigned short f2b(float f) {  // RNE f32->bf16
  unsigned u = __float_as_uint(f);
  return (unsigned short)((u + 0x7fffu + ((u >> 16) & 1u)) >> 16);
}
__device__ __forceinline__ float b2f(unsigned short us) {
  return __uint_as_float(((unsigned)us) << 16);
}

// convert weights to bf16; transposed (K-contiguous) layouts for MFMA B operands
__global__ void k_prep(const float* __restrict__ Wq, const float* __restrict__ Wk,
                       const float* __restrict__ W1, const float* __restrict__ W2,
                       unsigned short* __restrict__ Wq_b, unsigned short* __restrict__ Wk_b,
                       unsigned short* __restrict__ WkT_b, unsigned short* __restrict__ W1T_b,
                       unsigned short* __restrict__ W2T_b) {
  int i = blockIdx.x * blockDim.x + threadIdx.x;
  if (i < 65536) { Wq_b[i] = f2b(Wq[i]); return; }
  i -= 65536;
  if (i < 65536) { Wk_b[i] = f2b(Wk[i]); return; }
  i -= 65536;
  if (i < 65536) { int n = i >> 8, k = i & 255; WkT_b[i] = f2b(Wk[k * 256 + n]); return; }
  i -= 65536;
  if (i < 655360) { int n = i / 1280, k = i % 1280; W1T_b[i] = f2b(W1[k * 512 + n]); return; }
  i -= 655360;
  if (i < 131072) { int n = i >> 9, k = i & 511; W2T_b[i] = f2b(W2[k * 256 + n]); return; }
}

// bqk[a] = sum_b bq[b]*Wk[a][b] / 16   (one wave per output element)
__global__ void k_bqk(const float* __restrict__ bq, const float* __restrict__ Wk,
                      float* __restrict__ bqk) {
  int a = blockIdx.x;
  int lane = threadIdx.x;
  const float4 w = *(const float4*)(Wk + (size_t)a * 256 + lane * 4);
  const float4 b = *(const float4*)(bq + lane * 4);
  float p = w.x * b.x + w.y * b.y + w.z * b.z + w.w * b.w;
  #pragma unroll
  for (int o = 32; o; o >>= 1) p += __shfl_xor(p, o);
  if (lane == 0) bqk[a] = p * 0.0625f;
}

// segment offsets from sorted batch (every graph id present)
__global__ void k_offsets(const int* __restrict__ batch, int* __restrict__ offs, int N) {
  int i = blockIdx.x * blockDim.x + threadIdx.x;
  if (i >= N) return;
  if (i == 0) offs[0] = 0;
  else if (batch[i] != batch[i - 1]) offs[batch[i]] = i;
  if (i == N - 1) offs[GG] = N;
}

// ---------------- fused per-graph pooling: one block = one graph ----------------
// Phase A streams rows from HBM once, caching first CAP rows as bf16 in LDS.
// Phase C re-reads cached rows from LDS; overflow rows (most recently streamed,
// L3-hot) from global. 2 blocks/CU (LDS-bound).
__global__ __launch_bounds__(256, 2) void k_fused(
    const float* __restrict__ x, const int* __restrict__ offs,
    const float* __restrict__ w_attn, const unsigned short* __restrict__ M_b,
    const float* __restrict__ bqk,
    unsigned short* __restrict__ u_b, unsigned short* __restrict__ comb_b)
{
  const int g = blockIdx.x;
  const int s = offs[g], e = offs[g + 1];
  const int t = threadIdx.x;
  const int lane = t & 63, w = t >> 6;
  const int d0 = lane * 4;

  extern __shared__ float smem[];
  unsigned* cacheL = (unsigned*)smem;        // [CAP][128] uints = 64 KB
  float* redA = smem + 16384;                // [4][256]
  float* redB = redA + 1024;                 // [4][256]
  float* redC = redB + 1024;                 // [4][256]
  float* hm   = redC + 1024;                 // [256]
  float* qsL  = hm + 256;                    // [256]
  float* zA   = qsL + 256;                   // [4]
  float* z2A  = zA + 4;                      // [4]

  const float4 wa = *(const float4*)(w_attn + d0);
  const float NEG = -3.402823466e38f;
  const float4 Z4 = {0, 0, 0, 0};

  // ---- phase A: stream rows from HBM; sum, max, attn pool; cache bf16 in LDS ----
  float sx=0,sy=0,sz=0,sw=0, ax=0,ay=0,az=0,aw=0;
  float mx=NEG,my=NEG,mz=NEG,mw=NEG, ez=0.f;
  {
    int r = s + w;
    float4 b0 = (r      < e) ? *(const float4*)(x + (size_t)(r     ) * DD + d0) : Z4;
    float4 b1 = (r + 4  < e) ? *(const float4*)(x + (size_t)(r +  4) * DD + d0) : Z4;
    float4 b2 = (r + 8  < e) ? *(const float4*)(x + (size_t)(r +  8) * DD + d0) : Z4;
    float4 b3 = (r + 12 < e) ? *(const float4*)(x + (size_t)(r + 12) * DD + d0) : Z4;
    while (r < e) {
      const int rn = r + 16;
      float4 n0 = (rn      < e) ? *(const float4*)(x + (size_t)(rn     ) * DD + d0) : Z4;
      float4 n1 = (rn + 4  < e) ? *(const float4*)(x + (size_t)(rn +  4) * DD + d0) : Z4;
      float4 n2 = (rn + 8  < e) ? *(const float4*)(x + (size_t)(rn +  8) * DD + d0) : Z4;
      float4 n3 = (rn + 12 < e) ? *(const float4*)(x + (size_t)(rn + 12) * DD + d0) : Z4;
      #pragma unroll
      for (int i = 0; i < 4; ++i) {
        float4 v = (i == 0) ? b0 : (i == 1) ? b1 : (i == 2) ? b2 : b3;
        if (r + 4 * i < e) {        // wave-uniform guard
          int lr = r + 4 * i - s;
          if (lr < CAP) {           // cache as bf16
            unsigned lo = (unsigned)f2b(v.x) | ((unsigned)f2b(v.y) << 16);
            unsigned hi = (unsigned)f2b(v.z) | ((unsigned)f2b(v.w) << 16);
            cacheL[lr * 128 + 2 * lane    ] = lo;
            cacheL[lr * 128 + 2 * lane + 1] = hi;
          }
          float p = v.x*wa.x + v.y*wa.y + v.z*wa.z + v.w*wa.w;
          #pragma unroll
          for (int o = 32; o; o >>= 1) p += __shfl_xor(p, o);
          float ee = expf(p);       // softmax shift-invariance: unstabilized exp exact
          sx += v.x; sy += v.y; sz += v.z; sw += v.w;
          mx = fmaxf(mx, v.x); my = fmaxf(my, v.y);
          mz = fmaxf(mz, v.z); mw = fmaxf(mw, v.w);
          ax += v.x*ee; ay += v.y*ee; az += v.z*ee; aw += v.w*ee;
          ez += ee;
        }
      }
      b0 = n0; b1 = n1; b2 = n2; b3 = n3;
      r = rn;
    }
  }
  { float* p = &redA[w * 256 + d0]; p[0]=sx; p[1]=sy; p[2]=sz; p[3]=sw; }
  { float* p = &redB[w * 256 + d0]; p[0]=ax; p[1]=ay; p[2]=az; p[3]=aw; }
  { float* p = &redC[w * 256 + d0]; p[0]=mx; p[1]=my; p[2]=mz; p[3]=mw; }
  if (lane == 0) zA[w] = ez;
  __syncthreads();

  const float cnt = (float)(e - s);
  {
    float s4 = redA[t] + redA[256 + t] + redA[512 + t] + redA[768 + t];
    float a4 = redB[t] + redB[256 + t] + redB[512 + t] + redB[768 + t];
    float m4 = fmaxf(fmaxf(redC[t], redC[256 + t]), fmaxf(redC[512 + t], redC[768 + t]));
    float z1 = zA[0] + zA[1] + zA[2] + zA[3];
    float hmean = s4 / cnt;
    hm[t] = hmean;
    size_t c0 = (size_t)g * 1280;
    comb_b[c0 +        t] = f2b(hmean);
    comb_b[c0 +  256 + t] = f2b(m4);
    comb_b[c0 +  512 + t] = f2b(s4);
    comb_b[c0 +  768 + t] = f2b(a4 / z1);
  }
  __syncthreads();

  // ---- phase B: qs = hm @ M / 16 + bqk  (M bf16 128KB, L2-hot) ----
  {
    float acc = 0.f;
    #pragma unroll 8
    for (int a = 0; a < 256; ++a) acc += hm[a] * b2f(M_b[(size_t)a * 256 + t]);
    qsL[t] = acc * 0.0625f + bqk[t];
  }
  __syncthreads();

  // ---- phase C: s2s softmax-pool; cached rows from LDS, overflow from global ----
  float nx=0,ny=0,nz=0,nw=0, ez2=0.f;
  const float4 qv = *(const float4*)&qsL[d0];
  const int n = e - s;
  const int capn = (n < CAP) ? n : CAP;
  {
    // cached rows (each wave reads the rows it wrote: lr = w + 4i + 16k)
    int lr = w;
    uint2 c0 = (lr      < capn) ? *(const uint2*)&cacheL[(lr     ) * 128 + 2*lane] : (uint2){0,0};
    uint2 c1 = (lr + 4  < capn) ? *(const uint2*)&cacheL[(lr +  4) * 128 + 2*lane] : (uint2){0,0};
    uint2 c2 = (lr + 8  < capn) ? *(const uint2*)&cacheL[(lr +  8) * 128 + 2*lane] : (uint2){0,0};
    uint2 c3 = (lr + 12 < capn) ? *(const uint2*)&cacheL[(lr + 12) * 128 + 2*lane] : (uint2){0,0};
    while (lr < capn) {
      const int ln = lr + 16;
      uint2 m0 = (ln      < capn) ? *(const uint2*)&cacheL[(ln     ) * 128 + 2*lane] : (uint2){0,0};
      uint2 m1 = (ln + 4  < capn) ? *(const uint2*)&cacheL[(ln +  4) * 128 + 2*lane] : (uint2){0,0};
      uint2 m2 = (ln + 8  < capn) ? *(const uint2*)&cacheL[(ln +  8) * 128 + 2*lane] : (uint2){0,0};
      uint2 m3 = (ln + 12 < capn) ? *(const uint2*)&cacheL[(ln + 12) * 128 + 2*lane] : (uint2){0,0};
      #pragma unroll
      for (int i = 0; i < 4; ++i) {
        uint2 u = (i == 0) ? c0 : (i == 1) ? c1 : (i == 2) ? c2 : c3;
        if (lr + 4 * i < capn) {    // wave-uniform guard
          float vx = __uint_as_float(u.x << 16);
          float vy = __uint_as_float(u.x & 0xffff0000u);
          float vz = __uint_as_float(u.y << 16);
          float vw = __uint_as_float(u.y & 0xffff0000u);
          float p = vx*qv.x + vy*qv.y + vz*qv.z + vw*qv.w;
          #pragma unroll
          for (int o = 32; o; o >>= 1) p += __shfl_xor(p, o);
          float ee = expf(p);
          nx += vx*ee; ny += vy*ee; nz += vz*ee; nw += vw*ee;
          ez2 += ee;
        }
      }
      c0 = m0; c1 = m1; c2 = m2; c3 = m3;
      lr = ln;
    }
  }
  if (n > CAP) {
    // overflow rows: most recently streamed in phase A -> L3-hot
    int r = s + CAP + w;
    float4 b0 = (r      < e) ? *(const float4*)(x + (size_t)(r     ) * DD + d0) : Z4;
    float4 b1 = (r + 4  < e) ? *(const float4*)(x + (size_t)(r +  4) * DD + d0) : Z4;
    float4 b2 = (r + 8  < e) ? *(const float4*)(x + (size_t)(r +  8) * DD + d0) : Z4;
    float4 b3 = (r + 12 < e) ? *(const float4*)(x + (size_t)(r + 12) * DD + d0) : Z4;
    while (r < e) {
      const int rn = r + 16;
      float4 n0 = (rn      < e) ? *(const float4*)(x + (size_t)(rn     ) * DD + d0) : Z4;
      float4 n1 = (rn + 4  < e) ? *(const float4*)(x + (size_t)(rn +  4) * DD + d0) : Z4;
      float4 n2 = (rn + 8  < e) ? *(const float4*)(x + (size_t)(rn +  8) * DD + d0) : Z4;
      float4 n3 = (rn + 12 < e) ? *(const float4*)(x + (size_t)(rn + 12) * DD + d0) : Z4;
      #pragma unroll
      for (int i = 0; i < 4; ++i) {
        float4 v = (i == 0) ? b0 : (i == 1) ? b1 : (i == 2) ? b2 : b3;
        if (r + 4 * i < e) {        // wave-uniform guard
          float p = v.x*qv.x + v.y*qv.y + v.z*qv.z + v.w*qv.w;
          #pragma unroll
          for (int o = 32; o; o >>= 1) p += __shfl_xor(p, o);
          float ee = expf(p);
          nx += v.x*ee; ny += v.y*ee; nz += v.z*ee; nw += v.w*ee;
          ez2 += ee;
        }
      }
      b0 = n0; b1 = n1; b2 = n2; b3 = n3;
      r = rn;
    }
  }
  { float* p = &redA[w * 256 + d0]; p[0]=nx; p[1]=ny; p[2]=nz; p[3]=nw; }
  if (lane == 0) z2A[w] = ez2;
  __syncthreads();
  {
    float n4 = redA[t] + redA[256 + t] + redA[512 + t] + redA[768 + t];
    float z2 = z2A[0] + z2A[1] + z2A[2] + z2A[3];
    u_b[(size_t)g * DD + t] = f2b(n4 / z2);
  }
}

// ---------------- bf16 MFMA GEMM, LDS-free direct fragments ----------------
// A_b: [M][K] bf16 row-major; B_b: [N][K] bf16 row-major (op-B transposed).
// C = act(scale*A@B^T + bias).  OUT: 0 = f32 store, 1 = bf16 store.
template<int ACT, int OUT>
__global__ __launch_bounds__(256) void gemm_mfma(
    const unsigned short* __restrict__ Ab, const unsigned short* __restrict__ Bb,
    const float* __restrict__ bias, void* __restrict__ Cp,
    int K, int ldc, float scale)
{
  const int l  = threadIdx.x & 63;
  const int w  = threadIdx.x >> 6;
  const int m0 = blockIdx.y * 64 + (w >> 1) * 32;
  const int n0 = blockIdx.x * 64 + (w & 1) * 32;
  const int row = l & 15;
  const int kb  = (l >> 4) * 8;

  f32x4 acc00 = {}, acc01 = {}, acc10 = {}, acc11 = {};
  const unsigned short* pa0 = Ab + (size_t)(m0 + row) * K + kb;
  const unsigned short* pa1 = pa0 + (size_t)16 * K;
  const unsigned short* pb0 = Bb + (size_t)(n0 + row) * K + kb;
  const unsigned short* pb1 = pb0 + (size_t)16 * K;

  for (int k0 = 0; k0 < K; k0 += 32) {
    short8 a0 = *(const short8*)(pa0 + k0);
    short8 a1 = *(const short8*)(pa1 + k0);
    short8 b0 = *(const short8*)(pb0 + k0);
    short8 b1 = *(const short8*)(pb1 + k0);
    acc00 = __builtin_amdgcn_mfma_f32_16x16x32_bf16(a0, b0, acc00, 0, 0, 0);
    acc01 = __builtin_amdgcn_mfma_f32_16x16x32_bf16(a0, b1, acc01, 0, 0, 0);
    acc10 = __builtin_amdgcn_mfma_f32_16x16x32_bf16(a1, b0, acc10, 0, 0, 0);
    acc11 = __builtin_amdgcn_mfma_f32_16x16x32_bf16(a1, b1, acc11, 0, 0, 0);
  }

  f32x4 accs[2][2] = {{acc00, acc01}, {acc10, acc11}};
  #pragma unroll
  for (int i = 0; i < 2; ++i) {
    #pragma unroll
    for (int j = 0; j < 2; ++j) {
      int cn = n0 + 16 * j + (l & 15);
      float bv = bias ? bias[cn] : 0.f;
      #pragma unroll
      for (int r = 0; r < 4; ++r) {
        int cm = m0 + 16 * i + (l >> 4) * 4 + r;
        float v = accs[i][j][r] * scale + bv;
        if (ACT) v = 0.5f * v * (1.f + erff(v * 0.70710678118654752f));
        if (OUT == 0)      ((float*)Cp)[(size_t)cm * ldc + cn] = v;
        else               ((unsigned short*)Cp)[(size_t)cm * ldc + cn] = f2b(v);
      }
    }
  }
}

extern "C" void kernel_launch(void* const* d_in, const int* in_sizes, int n_in,
                              void* d_out, int out_size, void* d_ws, size_t ws_size,
                              hipStream_t stream)
{
  (void)n_in; (void)out_size; (void)ws_size;
  const float* x      = (const float*)d_in[0];
  const int*   batch  = (const int*)d_in[1];
  const float* w_attn = (const float*)d_in[3];
  // d_in[4] = b_attn: softmax shift-invariant, unused
  const float* Wq     = (const float*)d_in[5];
  const float* bq     = (const float*)d_in[6];
  const float* Wk     = (const float*)d_in[7];
  const float* bk     = (const float*)d_in[8];
  const float* W1     = (const float*)d_in[9];
  const float* b1     = (const float*)d_in[10];
  const float* W2     = (const float*)d_in[11];
  const float* b2     = (const float*)d_in[12];
  float* out = (float*)d_out;
  const int N = in_sizes[0] / DD;

  float* ws = (float*)d_ws;
  unsigned short* M_b = (unsigned short*)ws;          // 256x256 bf16 (32768 floats)
  float* bqk  = ws + 32768;                           // 256
  int*   offs = (int*)(ws + 32768 + 256);             // 2049 ints (pad 2304)
  float* base = ws + 32768 + 256 + 2304;
  unsigned short* u_b    = (unsigned short*)base;            // 2048*256 bf16
  unsigned short* comb_b = u_b + (size_t)GG * DD;            // 2048*1280
  unsigned short* h1_b   = comb_b + (size_t)GG * 1280;       // 2048*512
  unsigned short* Wq_b   = h1_b + (size_t)GG * 512;          // 65536
  unsigned short* Wk_b   = Wq_b + 65536;                     // 65536
  unsigned short* WkT_b  = Wk_b + 65536;                     // 65536
  unsigned short* W1T_b  = WkT_b + 65536;                    // 655360
  unsigned short* W2T_b  = W1T_b + 655360;                   // 131072

  k_prep<<<(983040 + 255) / 256, 256, 0, stream>>>(Wq, Wk, W1, W2, Wq_b, Wk_b, WkT_b, W1T_b, W2T_b);
  k_bqk<<<256, 64, 0, stream>>>(bq, Wk, bqk);
  k_offsets<<<(N + 255) / 256, 256, 0, stream>>>(batch, offs, N);
  // M = Wq @ Wk^T  (256x256, K=256), bf16 row-major M[a][c]
  gemm_mfma<0,1><<<dim3(4, 4), 256, 0, stream>>>(Wq_b, Wk_b, nullptr, M_b, 256, 256, 1.0f);
  // fused per-graph pooling (writes comb cols 0..1023 and u); 78.2 KB dynamic LDS
  k_fused<<<GG, 256, 79904, stream>>>(x, offs, w_attn, M_b, bqk, u_b, comb_b);
  // h_s2s = u @ Wk + bk -> comb cols [1024,1280), bf16
  gemm_mfma<0,1><<<dim3(4, 32), 256, 0, stream>>>(u_b, WkT_b, bk, comb_b + 4 * DD, 256, 1280, 1.0f);
  // h1 = gelu(comb @ W1 + b1), bf16
  gemm_mfma<1,1><<<dim3(8, 32), 256, 0, stream>>>(comb_b, W1T_b, b1, h1_b, 1280, 512, 1.0f);
  // out = h1 @ W2 + b2, f32
  gemm_mfma<0,0><<<dim3(4, 32), 256, 0, stream>>>(h1_b, W2T_b, b2, out, 512, 256, 1.0f);
}

// Round 6
// 232.020 us; speedup vs baseline: 1.1969x; 1.1969x over previous
//
#include <hip/hip_runtime.h>
#include <math.h>

#define DD 256
#define GG 2048

typedef __attribute__((ext_vector_type(8))) short short8;
typedef __attribute__((ext_vector_type(4))) float f32x4;

__device__ __forceinline__ unsigned short f2b(float f) {  // RNE f32->bf16
  unsigned u = __float_as_uint(f);
  return (unsigned short)((u + 0x7fffu + ((u >> 16) & 1u)) >> 16);
}
__device__ __forceinline__ float b2f(unsigned short us) {
  return __uint_as_float(((unsigned)us) << 16);
}

// ---- 64-lane sum via DPP on the VALU pipe (no ds_swizzle -> no LDS-pipe serialization) ----
template<int CTRL>
__device__ __forceinline__ float dppadd(float v) {
  int t = __builtin_amdgcn_update_dpp(0, __float_as_int(v), CTRL, 0xF, 0xF, true);
  return v + __int_as_float(t);
}
__device__ __forceinline__ float red64(float v) {
  v = dppadd<0xB1>(v);    // quad_perm [1,0,3,2]  (xor 1)
  v = dppadd<0x4E>(v);    // quad_perm [2,3,0,1]  (xor 2)
  v = dppadd<0x141>(v);   // row_half_mirror      (combine quads in 8)
  v = dppadd<0x140>(v);   // row_mirror           -> each 16-lane row holds row-sum
  v = dppadd<0x142>(v);   // row_bcast15          -> lane31/63 hold 32-sums
  v = dppadd<0x143>(v);   // row_bcast31          -> lane63 holds 64-sum
  return __int_as_float(__builtin_amdgcn_readlane(__float_as_int(v), 63));
}

// convert weights to bf16; transposed (K-contiguous) layouts for MFMA B operands
__global__ void k_prep(const float* __restrict__ Wq, const float* __restrict__ Wk,
                       const float* __restrict__ W1, const float* __restrict__ W2,
                       unsigned short* __restrict__ Wq_b, unsigned short* __restrict__ Wk_b,
                       unsigned short* __restrict__ WkT_b, unsigned short* __restrict__ W1T_b,
                       unsigned short* __restrict__ W2T_b) {
  int i = blockIdx.x * blockDim.x + threadIdx.x;
  if (i < 65536) { Wq_b[i] = f2b(Wq[i]); return; }
  i -= 65536;
  if (i < 65536) { Wk_b[i] = f2b(Wk[i]); return; }
  i -= 65536;
  if (i < 65536) { int n = i >> 8, k = i & 255; WkT_b[i] = f2b(Wk[k * 256 + n]); return; }
  i -= 65536;
  if (i < 655360) { int n = i / 1280, k = i % 1280; W1T_b[i] = f2b(W1[k * 512 + n]); return; }
  i -= 655360;
  if (i < 131072) { int n = i >> 9, k = i & 511; W2T_b[i] = f2b(W2[k * 256 + n]); return; }
}

// bqk[a] = sum_b bq[b]*Wk[a][b] / 16   (one wave per output element)
__global__ void k_bqk(const float* __restrict__ bq, const float* __restrict__ Wk,
                      float* __restrict__ bqk) {
  int a = blockIdx.x;
  int lane = threadIdx.x;
  const float4 w = *(const float4*)(Wk + (size_t)a * 256 + lane * 4);
  const float4 b = *(const float4*)(bq + lane * 4);
  float p = w.x * b.x + w.y * b.y + w.z * b.z + w.w * b.w;
  #pragma unroll
  for (int o = 32; o; o >>= 1) p += __shfl_xor(p, o);
  if (lane == 0) bqk[a] = p * 0.0625f;
}

// segment offsets from sorted batch (every graph id present)
__global__ void k_offsets(const int* __restrict__ batch, int* __restrict__ offs, int N) {
  int i = blockIdx.x * blockDim.x + threadIdx.x;
  if (i >= N) return;
  if (i == 0) offs[0] = 0;
  else if (batch[i] != batch[i - 1]) offs[batch[i]] = i;
  if (i == N - 1) offs[GG] = N;
}

// ---------------- fused per-graph pooling: one block = one graph ----------------
// 8 blocks/CU (32 waves) + 4-deep row pipeline + DPP reduces (VALU pipe only).
__global__ __launch_bounds__(256, 8) void k_fused(
    const float* __restrict__ x, const int* __restrict__ offs,
    const float* __restrict__ w_attn, const unsigned short* __restrict__ M_b,
    const float* __restrict__ bqk,
    unsigned short* __restrict__ u_b, unsigned short* __restrict__ comb_b)
{
  const int g = blockIdx.x;
  const int s = offs[g], e = offs[g + 1];
  const int t = threadIdx.x;
  const int lane = t & 63, w = t >> 6;
  const int d0 = lane * 4;

  __shared__ float redA[4][256];   // sum / s2s-num
  __shared__ float redB[4][256];   // attn-num
  __shared__ float redC[4][256];   // max
  __shared__ float hm[256];
  __shared__ float qsL[256];
  __shared__ float zA[4], z2A[4];

  const float4 wa = *(const float4*)(w_attn + d0);
  const float NEG = -3.402823466e38f;
  const float4 Z4 = {0, 0, 0, 0};

  // ---- phase A: stream rows from HBM; sum, max, attn softmax-pool ----
  float sx=0,sy=0,sz=0,sw=0, ax=0,ay=0,az=0,aw=0;
  float mx=NEG,my=NEG,mz=NEG,mw=NEG, ez=0.f;
  {
    int r = s + w;
    float4 b0 = (r      < e) ? *(const float4*)(x + (size_t)(r     ) * DD + d0) : Z4;
    float4 b1 = (r + 4  < e) ? *(const float4*)(x + (size_t)(r +  4) * DD + d0) : Z4;
    float4 b2 = (r + 8  < e) ? *(const float4*)(x + (size_t)(r +  8) * DD + d0) : Z4;
    float4 b3 = (r + 12 < e) ? *(const float4*)(x + (size_t)(r + 12) * DD + d0) : Z4;
    while (r < e) {
      const int rn = r + 16;
      float4 n0 = (rn      < e) ? *(const float4*)(x + (size_t)(rn     ) * DD + d0) : Z4;
      float4 n1 = (rn + 4  < e) ? *(const float4*)(x + (size_t)(rn +  4) * DD + d0) : Z4;
      float4 n2 = (rn + 8  < e) ? *(const float4*)(x + (size_t)(rn +  8) * DD + d0) : Z4;
      float4 n3 = (rn + 12 < e) ? *(const float4*)(x + (size_t)(rn + 12) * DD + d0) : Z4;
      #pragma unroll
      for (int i = 0; i < 4; ++i) {
        float4 v = (i == 0) ? b0 : (i == 1) ? b1 : (i == 2) ? b2 : b3;
        if (r + 4 * i < e) {        // wave-uniform guard
          float p = red64(v.x*wa.x + v.y*wa.y + v.z*wa.z + v.w*wa.w);
          float ee = __expf(p);     // softmax shift-invariance: unstabilized exp exact
          sx += v.x; sy += v.y; sz += v.z; sw += v.w;
          mx = fmaxf(mx, v.x); my = fmaxf(my, v.y);
          mz = fmaxf(mz, v.z); mw = fmaxf(mw, v.w);
          ax += v.x*ee; ay += v.y*ee; az += v.z*ee; aw += v.w*ee;
          ez += ee;
        }
      }
      b0 = n0; b1 = n1; b2 = n2; b3 = n3;
      r = rn;
    }
  }
  { float* p = &redA[w][d0]; p[0]=sx; p[1]=sy; p[2]=sz; p[3]=sw; }
  { float* p = &redB[w][d0]; p[0]=ax; p[1]=ay; p[2]=az; p[3]=aw; }
  { float* p = &redC[w][d0]; p[0]=mx; p[1]=my; p[2]=mz; p[3]=mw; }
  if (lane == 0) zA[w] = ez;
  __syncthreads();

  const float cnt = (float)(e - s);
  {
    float s4 = redA[0][t] + redA[1][t] + redA[2][t] + redA[3][t];
    float a4 = redB[0][t] + redB[1][t] + redB[2][t] + redB[3][t];
    float m4 = fmaxf(fmaxf(redC[0][t], redC[1][t]), fmaxf(redC[2][t], redC[3][t]));
    float z1 = zA[0] + zA[1] + zA[2] + zA[3];
    float hmean = s4 / cnt;
    hm[t] = hmean;
    size_t c0 = (size_t)g * 1280;
    comb_b[c0 +        t] = f2b(hmean);
    comb_b[c0 +  256 + t] = f2b(m4);
    comb_b[c0 +  512 + t] = f2b(s4);
    comb_b[c0 +  768 + t] = f2b(a4 / z1);
  }
  __syncthreads();

  // ---- phase B: qs = hm @ M / 16 + bqk  (M bf16 128KB, L2-hot) ----
  {
    float acc = 0.f;
    #pragma unroll 8
    for (int a = 0; a < 256; ++a) acc += hm[a] * b2f(M_b[(size_t)a * 256 + t]);
    qsL[t] = acc * 0.0625f + bqk[t];
  }
  __syncthreads();

  // ---- phase C: re-read rows (L3-assisted); s2s softmax-pool ----
  float nx=0,ny=0,nz=0,nw=0, ez2=0.f;
  {
    const float4 qv = *(const float4*)&qsL[d0];
    int r = s + w;
    float4 b0 = (r      < e) ? *(const float4*)(x + (size_t)(r     ) * DD + d0) : Z4;
    float4 b1 = (r + 4  < e) ? *(const float4*)(x + (size_t)(r +  4) * DD + d0) : Z4;
    float4 b2 = (r + 8  < e) ? *(const float4*)(x + (size_t)(r +  8) * DD + d0) : Z4;
    float4 b3 = (r + 12 < e) ? *(const float4*)(x + (size_t)(r + 12) * DD + d0) : Z4;
    while (r < e) {
      const int rn = r + 16;
      float4 n0 = (rn      < e) ? *(const float4*)(x + (size_t)(rn     ) * DD + d0) : Z4;
      float4 n1 = (rn + 4  < e) ? *(const float4*)(x + (size_t)(rn +  4) * DD + d0) : Z4;
      float4 n2 = (rn + 8  < e) ? *(const float4*)(x + (size_t)(rn +  8) * DD + d0) : Z4;
      float4 n3 = (rn + 12 < e) ? *(const float4*)(x + (size_t)(rn + 12) * DD + d0) : Z4;
      #pragma unroll
      for (int i = 0; i < 4; ++i) {
        float4 v = (i == 0) ? b0 : (i == 1) ? b1 : (i == 2) ? b2 : b3;
        if (r + 4 * i < e) {        // wave-uniform guard
          float p = red64(v.x*qv.x + v.y*qv.y + v.z*qv.z + v.w*qv.w);
          float ee = __expf(p);
          nx += v.x*ee; ny += v.y*ee; nz += v.z*ee; nw += v.w*ee;
          ez2 += ee;
        }
      }
      b0 = n0; b1 = n1; b2 = n2; b3 = n3;
      r = rn;
    }
  }
  { float* p = &redA[w][d0]; p[0]=nx; p[1]=ny; p[2]=nz; p[3]=nw; }
  if (lane == 0) z2A[w] = ez2;
  __syncthreads();
  {
    float n4 = redA[0][t] + redA[1][t] + redA[2][t] + redA[3][t];
    float z2 = z2A[0] + z2A[1] + z2A[2] + z2A[3];
    u_b[(size_t)g * DD + t] = f2b(n4 / z2);
  }
}

// ---------------- bf16 MFMA GEMM, LDS-free direct fragments ----------------
// A_b: [M][K] bf16 row-major; B_b: [N][K] bf16 row-major (op-B transposed).
// C = act(scale*A@B^T + bias).  OUT: 0 = f32 store, 1 = bf16 store.
template<int ACT, int OUT>
__global__ __launch_bounds__(256) void gemm_mfma(
    const unsigned short* __restrict__ Ab, const unsigned short* __restrict__ Bb,
    const float* __restrict__ bias, void* __restrict__ Cp,
    int K, int ldc, float scale)
{
  const int l  = threadIdx.x & 63;
  const int w  = threadIdx.x >> 6;
  const int m0 = blockIdx.y * 64 + (w >> 1) * 32;
  const int n0 = blockIdx.x * 64 + (w & 1) * 32;
  const int row = l & 15;
  const int kb  = (l >> 4) * 8;

  f32x4 acc00 = {}, acc01 = {}, acc10 = {}, acc11 = {};
  const unsigned short* pa0 = Ab + (size_t)(m0 + row) * K + kb;
  const unsigned short* pa1 = pa0 + (size_t)16 * K;
  const unsigned short* pb0 = Bb + (size_t)(n0 + row) * K + kb;
  const unsigned short* pb1 = pb0 + (size_t)16 * K;

  for (int k0 = 0; k0 < K; k0 += 32) {
    short8 a0 = *(const short8*)(pa0 + k0);
    short8 a1 = *(const short8*)(pa1 + k0);
    short8 b0 = *(const short8*)(pb0 + k0);
    short8 b1 = *(const short8*)(pb1 + k0);
    acc00 = __builtin_amdgcn_mfma_f32_16x16x32_bf16(a0, b0, acc00, 0, 0, 0);
    acc01 = __builtin_amdgcn_mfma_f32_16x16x32_bf16(a0, b1, acc01, 0, 0, 0);
    acc10 = __builtin_amdgcn_mfma_f32_16x16x32_bf16(a1, b0, acc10, 0, 0, 0);
    acc11 = __builtin_amdgcn_mfma_f32_16x16x32_bf16(a1, b1, acc11, 0, 0, 0);
  }

  f32x4 accs[2][2] = {{acc00, acc01}, {acc10, acc11}};
  #pragma unroll
  for (int i = 0; i < 2; ++i) {
    #pragma unroll
    for (int j = 0; j < 2; ++j) {
      int cn = n0 + 16 * j + (l & 15);
      float bv = bias ? bias[cn] : 0.f;
      #pragma unroll
      for (int r = 0; r < 4; ++r) {
        int cm = m0 + 16 * i + (l >> 4) * 4 + r;
        float v = accs[i][j][r] * scale + bv;
        if (ACT) v = 0.5f * v * (1.f + erff(v * 0.70710678118654752f));
        if (OUT == 0)      ((float*)Cp)[(size_t)cm * ldc + cn] = v;
        else               ((unsigned short*)Cp)[(size_t)cm * ldc + cn] = f2b(v);
      }
    }
  }
}

extern "C" void kernel_launch(void* const* d_in, const int* in_sizes, int n_in,
                              void* d_out, int out_size, void* d_ws, size_t ws_size,
                              hipStream_t stream)
{
  (void)n_in; (void)out_size; (void)ws_size;
  const float* x      = (const float*)d_in[0];
  const int*   batch  = (const int*)d_in[1];
  const float* w_attn = (const float*)d_in[3];
  // d_in[4] = b_attn: softmax shift-invariant, unused
  const float* Wq     = (const float*)d_in[5];
  const float* bq     = (const float*)d_in[6];
  const float* Wk     = (const float*)d_in[7];
  const float* bk     = (const float*)d_in[8];
  const float* W1     = (const float*)d_in[9];
  const float* b1     = (const float*)d_in[10];
  const float* W2     = (const float*)d_in[11];
  const float* b2     = (const float*)d_in[12];
  float* out = (float*)d_out;
  const int N = in_sizes[0] / DD;

  float* ws = (float*)d_ws;
  unsigned short* M_b = (unsigned short*)ws;          // 256x256 bf16 (32768 floats)
  float* bqk  = ws + 32768;                           // 256
  int*   offs = (int*)(ws + 32768 + 256);             // 2049 ints (pad 2304)
  float* base = ws + 32768 + 256 + 2304;
  unsigned short* u_b    = (unsigned short*)base;            // 2048*256 bf16
  unsigned short* comb_b = u_b + (size_t)GG * DD;            // 2048*1280
  unsigned short* h1_b   = comb_b + (size_t)GG * 1280;       // 2048*512
  unsigned short* Wq_b   = h1_b + (size_t)GG * 512;          // 65536
  unsigned short* Wk_b   = Wq_b + 65536;                     // 65536
  unsigned short* WkT_b  = Wk_b + 65536;                     // 65536
  unsigned short* W1T_b  = WkT_b + 65536;                    // 655360
  unsigned short* W2T_b  = W1T_b + 655360;                   // 131072

  k_prep<<<(983040 + 255) / 256, 256, 0, stream>>>(Wq, Wk, W1, W2, Wq_b, Wk_b, WkT_b, W1T_b, W2T_b);
  k_bqk<<<256, 64, 0, stream>>>(bq, Wk, bqk);
  k_offsets<<<(N + 255) / 256, 256, 0, stream>>>(batch, offs, N);
  // M = Wq @ Wk^T  (256x256, K=256), bf16 row-major M[a][c]
  gemm_mfma<0,1><<<dim3(4, 4), 256, 0, stream>>>(Wq_b, Wk_b, nullptr, M_b, 256, 256, 1.0f);
  // fused per-graph pooling (writes comb cols 0..1023 and u)
  k_fused<<<GG, 256, 0, stream>>>(x, offs, w_attn, M_b, bqk, u_b, comb_b);
  // h_s2s = u @ Wk + bk -> comb cols [1024,1280), bf16
  gemm_mfma<0,1><<<dim3(4, 32), 256, 0, stream>>>(u_b, WkT_b, bk, comb_b + 4 * DD, 256, 1280, 1.0f);
  // h1 = gelu(comb @ W1 + b1), bf16
  gemm_mfma<1,1><<<dim3(8, 32), 256, 0, stream>>>(comb_b, W1T_b, b1, h1_b, 1280, 512, 1.0f);
  // out = h1 @ W2 + b2, f32
  gemm_mfma<0,0><<<dim3(4, 32), 256, 0, stream>>>(h1_b, W2T_b, b2, out, 512, 256, 1.0f);
}

// Round 7
// 208.294 us; speedup vs baseline: 1.3333x; 1.1139x over previous
//
#include <hip/hip_runtime.h>
#include <math.h>

#define DD 256
#define GG 2048

typedef __attribute__((ext_vector_type(8))) short short8;
typedef __attribute__((ext_vector_type(4))) float f32x4;

__device__ __forceinline__ unsigned short f2b(float f) {  // RNE f32->bf16
  unsigned u = __float_as_uint(f);
  return (unsigned short)((u + 0x7fffu + ((u >> 16) & 1u)) >> 16);
}
__device__ __forceinline__ float b2f(unsigned short us) {
  return __uint_as_float(((unsigned)us) << 16);
}

// ---- 16-lane row-sum via DPP (VALU pipe, 4 dependent ops, result in all 16 lanes) ----
template<int CTRL>
__device__ __forceinline__ float dppadd(float v) {
  int t = __builtin_amdgcn_update_dpp(0, __float_as_int(v), CTRL, 0xF, 0xF, true);
  return v + __int_as_float(t);
}
__device__ __forceinline__ float red16(float v) {
  v = dppadd<0xB1>(v);    // quad_perm [1,0,3,2]
  v = dppadd<0x4E>(v);    // quad_perm [2,3,0,1]
  v = dppadd<0x141>(v);   // row_half_mirror (combine quads in 8)
  v = dppadd<0x140>(v);   // row_mirror (combine 8s in 16)
  return v;
}
__device__ __forceinline__ float dot4(float4 a, float4 b) {
  return a.x*b.x + a.y*b.y + a.z*b.z + a.w*b.w;
}
// sum across the 4 row-groups of a wave (lanes ^16, ^32)
__device__ __forceinline__ float4 xsum4(float4 v) {
  v.x += __shfl_xor(v.x,16); v.y += __shfl_xor(v.y,16);
  v.z += __shfl_xor(v.z,16); v.w += __shfl_xor(v.w,16);
  v.x += __shfl_xor(v.x,32); v.y += __shfl_xor(v.y,32);
  v.z += __shfl_xor(v.z,32); v.w += __shfl_xor(v.w,32);
  return v;
}
__device__ __forceinline__ float4 xmax4(float4 v) {
  v.x = fmaxf(v.x, __shfl_xor(v.x,16)); v.y = fmaxf(v.y, __shfl_xor(v.y,16));
  v.z = fmaxf(v.z, __shfl_xor(v.z,16)); v.w = fmaxf(v.w, __shfl_xor(v.w,16));
  v.x = fmaxf(v.x, __shfl_xor(v.x,32)); v.y = fmaxf(v.y, __shfl_xor(v.y,32));
  v.z = fmaxf(v.z, __shfl_xor(v.z,32)); v.w = fmaxf(v.w, __shfl_xor(v.w,32));
  return v;
}

// convert weights to bf16; transposed (K-contiguous) layouts for MFMA B operands
__global__ void k_prep(const float* __restrict__ Wq, const float* __restrict__ Wk,
                       const float* __restrict__ W1, const float* __restrict__ W2,
                       unsigned short* __restrict__ Wq_b, unsigned short* __restrict__ Wk_b,
                       unsigned short* __restrict__ WkT_b, unsigned short* __restrict__ W1T_b,
                       unsigned short* __restrict__ W2T_b) {
  int i = blockIdx.x * blockDim.x + threadIdx.x;
  if (i < 65536) { Wq_b[i] = f2b(Wq[i]); return; }
  i -= 65536;
  if (i < 65536) { Wk_b[i] = f2b(Wk[i]); return; }
  i -= 65536;
  if (i < 65536) { int n = i >> 8, k = i & 255; WkT_b[i] = f2b(Wk[k * 256 + n]); return; }
  i -= 65536;
  if (i < 655360) { int n = i / 1280, k = i % 1280; W1T_b[i] = f2b(W1[k * 512 + n]); return; }
  i -= 655360;
  if (i < 131072) { int n = i >> 9, k = i & 511; W2T_b[i] = f2b(W2[k * 256 + n]); return; }
}

// bqk[a] = sum_b bq[b]*Wk[a][b] / 16   (one wave per output element)
__global__ void k_bqk(const float* __restrict__ bq, const float* __restrict__ Wk,
                      float* __restrict__ bqk) {
  int a = blockIdx.x;
  int lane = threadIdx.x;
  const float4 w = *(const float4*)(Wk + (size_t)a * 256 + lane * 4);
  const float4 b = *(const float4*)(bq + lane * 4);
  float p = w.x * b.x + w.y * b.y + w.z * b.z + w.w * b.w;
  #pragma unroll
  for (int o = 32; o; o >>= 1) p += __shfl_xor(p, o);
  if (lane == 0) bqk[a] = p * 0.0625f;
}

// segment offsets from sorted batch (every graph id present)
__global__ void k_offsets(const int* __restrict__ batch, int* __restrict__ offs, int N) {
  int i = blockIdx.x * blockDim.x + threadIdx.x;
  if (i >= N) return;
  if (i == 0) offs[0] = 0;
  else if (batch[i] != batch[i - 1]) offs[batch[i]] = i;
  if (i == N - 1) offs[GG] = N;
}

// ---------------- fused per-graph pooling: one block = one graph ----------------
// 16 lanes per row: per-row reduce = 4 DPP ops (VALU), col accumulators per-lane.
__global__ __launch_bounds__(256, 3) void k_fused(
    const float* __restrict__ x, const int* __restrict__ offs,
    const float* __restrict__ w_attn, const unsigned short* __restrict__ M_b,
    const float* __restrict__ bqk,
    unsigned short* __restrict__ u_b, unsigned short* __restrict__ comb_b)
{
  const int g = blockIdx.x;
  const int s = offs[g], e = offs[g + 1];
  const int t = threadIdx.x;
  const int l = t & 63, w = t >> 6;
  const int grp = l >> 4;            // row-group within wave (0..3)
  const int c0 = (l & 15) * 4;       // col base; lane owns cols c0 + {0,64,128,192}
  const int myoff = w * 4 + grp;     // row offset within a 16-row block step

  __shared__ float redA[4][256];
  __shared__ float redB[4][256];
  __shared__ float redC[4][256];
  __shared__ float hm[256];
  __shared__ float qsL[256];
  __shared__ float zA[4], z2A[4];

  const float NEG = -3.402823466e38f;
  const float4 Z4 = {0, 0, 0, 0};

  const float4 wa0 = *(const float4*)(w_attn + c0);
  const float4 wa1 = *(const float4*)(w_attn + c0 + 64);
  const float4 wa2 = *(const float4*)(w_attn + c0 + 128);
  const float4 wa3 = *(const float4*)(w_attn + c0 + 192);

  // guarded batch load: row clamped in-bounds, value zeroed if invalid
#define LOADB(d0_,d1_,d2_,d3_,ok_,rr_) {                         \
    int rc_ = ((rr_) < e) ? (rr_) : (e - 1);                     \
    ok_ = (rr_) < e;                                             \
    const float* bp_ = x + (size_t)rc_ * DD + c0;                \
    d0_ = *(const float4*)(bp_);                                 \
    d1_ = *(const float4*)(bp_ + 64);                            \
    d2_ = *(const float4*)(bp_ + 128);                           \
    d3_ = *(const float4*)(bp_ + 192);                           \
    if (!ok_) { d0_ = Z4; d1_ = Z4; d2_ = Z4; d3_ = Z4; }        \
  }

  // ---- phase A: stream rows; col-sums, col-max, attn softmax-pool ----
  float4 s0=Z4,s1=Z4,s2=Z4,s3=Z4;
  float4 a0=Z4,a1=Z4,a2=Z4,a3=Z4;
  float4 m0={NEG,NEG,NEG,NEG}, m1=m0, m2=m0, m3=m0;
  float ez = 0.f;
  {
    float4 u0,u1,u2,u3, n0,n1,n2,n3; bool oku, okn;
    LOADB(u0,u1,u2,u3,oku, s + myoff);
    if (s + 16 < e) { LOADB(n0,n1,n2,n3,okn, s + 16 + myoff); }
    else { n0=n1=n2=n3=Z4; okn=false; }
    for (int rb = s; rb < e; rb += 16) {
      float p = dot4(u0,wa0) + dot4(u1,wa1) + dot4(u2,wa2) + dot4(u3,wa3);
      p = red16(p);
      float ee = __expf(p);          // softmax shift-invariance: unstabilized exp exact
      ez += oku ? ee : 0.f;
      s0 += u0; s1 += u1; s2 += u2; s3 += u3;
      a0.x += u0.x*ee; a0.y += u0.y*ee; a0.z += u0.z*ee; a0.w += u0.w*ee;
      a1.x += u1.x*ee; a1.y += u1.y*ee; a1.z += u1.z*ee; a1.w += u1.w*ee;
      a2.x += u2.x*ee; a2.y += u2.y*ee; a2.z += u2.z*ee; a2.w += u2.w*ee;
      a3.x += u3.x*ee; a3.y += u3.y*ee; a3.z += u3.z*ee; a3.w += u3.w*ee;
      if (oku) {
        m0.x=fmaxf(m0.x,u0.x); m0.y=fmaxf(m0.y,u0.y); m0.z=fmaxf(m0.z,u0.z); m0.w=fmaxf(m0.w,u0.w);
        m1.x=fmaxf(m1.x,u1.x); m1.y=fmaxf(m1.y,u1.y); m1.z=fmaxf(m1.z,u1.z); m1.w=fmaxf(m1.w,u1.w);
        m2.x=fmaxf(m2.x,u2.x); m2.y=fmaxf(m2.y,u2.y); m2.z=fmaxf(m2.z,u2.z); m2.w=fmaxf(m2.w,u2.w);
        m3.x=fmaxf(m3.x,u3.x); m3.y=fmaxf(m3.y,u3.y); m3.z=fmaxf(m3.z,u3.z); m3.w=fmaxf(m3.w,u3.w);
      }
      u0=n0; u1=n1; u2=n2; u3=n3; oku=okn;
      if (rb + 32 < e) { LOADB(n0,n1,n2,n3,okn, rb + 32 + myoff); }
      else { n0=n1=n2=n3=Z4; okn=false; }
    }
  }
  // combine across the wave's 4 row-groups (once per phase)
  s0=xsum4(s0); s1=xsum4(s1); s2=xsum4(s2); s3=xsum4(s3);
  a0=xsum4(a0); a1=xsum4(a1); a2=xsum4(a2); a3=xsum4(a3);
  m0=xmax4(m0); m1=xmax4(m1); m2=xmax4(m2); m3=xmax4(m3);
  ez += __shfl_xor(ez,16); ez += __shfl_xor(ez,32);
  if (l < 16) {
    *(float4*)&redA[w][c0      ] = s0; *(float4*)&redA[w][c0 + 64 ] = s1;
    *(float4*)&redA[w][c0 + 128] = s2; *(float4*)&redA[w][c0 + 192] = s3;
    *(float4*)&redB[w][c0      ] = a0; *(float4*)&redB[w][c0 + 64 ] = a1;
    *(float4*)&redB[w][c0 + 128] = a2; *(float4*)&redB[w][c0 + 192] = a3;
    *(float4*)&redC[w][c0      ] = m0; *(float4*)&redC[w][c0 + 64 ] = m1;
    *(float4*)&redC[w][c0 + 128] = m2; *(float4*)&redC[w][c0 + 192] = m3;
    if (l == 0) zA[w] = ez;
  }
  __syncthreads();

  const float cnt = (float)(e - s);
  {
    float s4 = redA[0][t] + redA[1][t] + redA[2][t] + redA[3][t];
    float a4 = redB[0][t] + redB[1][t] + redB[2][t] + redB[3][t];
    float m4 = fmaxf(fmaxf(redC[0][t], redC[1][t]), fmaxf(redC[2][t], redC[3][t]));
    float z1 = zA[0] + zA[1] + zA[2] + zA[3];
    float hmean = s4 / cnt;
    hm[t] = hmean;
    size_t cb = (size_t)g * 1280;
    comb_b[cb +        t] = f2b(hmean);
    comb_b[cb +  256 + t] = f2b(m4);
    comb_b[cb +  512 + t] = f2b(s4);
    comb_b[cb +  768 + t] = f2b(a4 / z1);
  }
  __syncthreads();

  // ---- phase B: qs = hm @ M / 16 + bqk  (M bf16 128KB, L2-hot) ----
  {
    float acc = 0.f;
    #pragma unroll 8
    for (int a = 0; a < 256; ++a) acc += hm[a] * b2f(M_b[(size_t)a * 256 + t]);
    qsL[t] = acc * 0.0625f + bqk[t];
  }
  __syncthreads();

  // ---- phase C: re-read rows (L3-served); s2s softmax-pool ----
  float4 v0=Z4,v1=Z4,v2=Z4,v3=Z4;
  float ez2 = 0.f;
  {
    const float4 q0 = *(const float4*)&qsL[c0];
    const float4 q1 = *(const float4*)&qsL[c0 + 64];
    const float4 q2 = *(const float4*)&qsL[c0 + 128];
    const float4 q3 = *(const float4*)&qsL[c0 + 192];
    float4 u0,u1,u2,u3, n0,n1,n2,n3; bool oku, okn;
    LOADB(u0,u1,u2,u3,oku, s + myoff);
    if (s + 16 < e) { LOADB(n0,n1,n2,n3,okn, s + 16 + myoff); }
    else { n0=n1=n2=n3=Z4; okn=false; }
    for (int rb = s; rb < e; rb += 16) {
      float p = dot4(u0,q0) + dot4(u1,q1) + dot4(u2,q2) + dot4(u3,q3);
      p = red16(p);
      float ee = __expf(p);
      ez2 += oku ? ee : 0.f;
      v0.x += u0.x*ee; v0.y += u0.y*ee; v0.z += u0.z*ee; v0.w += u0.w*ee;
      v1.x += u1.x*ee; v1.y += u1.y*ee; v1.z += u1.z*ee; v1.w += u1.w*ee;
      v2.x += u2.x*ee; v2.y += u2.y*ee; v2.z += u2.z*ee; v2.w += u2.w*ee;
      v3.x += u3.x*ee; v3.y += u3.y*ee; v3.z += u3.z*ee; v3.w += u3.w*ee;
      u0=n0; u1=n1; u2=n2; u3=n3; oku=okn;
      if (rb + 32 < e) { LOADB(n0,n1,n2,n3,okn, rb + 32 + myoff); }
      else { n0=n1=n2=n3=Z4; okn=false; }
    }
  }
  v0=xsum4(v0); v1=xsum4(v1); v2=xsum4(v2); v3=xsum4(v3);
  ez2 += __shfl_xor(ez2,16); ez2 += __shfl_xor(ez2,32);
  if (l < 16) {
    *(float4*)&redA[w][c0      ] = v0; *(float4*)&redA[w][c0 + 64 ] = v1;
    *(float4*)&redA[w][c0 + 128] = v2; *(float4*)&redA[w][c0 + 192] = v3;
    if (l == 0) z2A[w] = ez2;
  }
  __syncthreads();
  {
    float n4 = redA[0][t] + redA[1][t] + redA[2][t] + redA[3][t];
    float z2 = z2A[0] + z2A[1] + z2A[2] + z2A[3];
    u_b[(size_t)g * DD + t] = f2b(n4 / z2);
  }
#undef LOADB
}

// ---------------- bf16 MFMA GEMM, LDS-free direct fragments ----------------
// A_b: [M][K] bf16 row-major; B_b: [N][K] bf16 row-major (op-B transposed).
// C = act(scale*A@B^T + bias).  OUT: 0 = f32 store, 1 = bf16 store.
template<int ACT, int OUT>
__global__ __launch_bounds__(256) void gemm_mfma(
    const unsigned short* __restrict__ Ab, const unsigned short* __restrict__ Bb,
    const float* __restrict__ bias, void* __restrict__ Cp,
    int K, int ldc, float scale)
{
  const int l  = threadIdx.x & 63;
  const int w  = threadIdx.x >> 6;
  const int m0 = blockIdx.y * 64 + (w >> 1) * 32;
  const int n0 = blockIdx.x * 64 + (w & 1) * 32;
  const int row = l & 15;
  const int kb  = (l >> 4) * 8;

  f32x4 acc00 = {}, acc01 = {}, acc10 = {}, acc11 = {};
  const unsigned short* pa0 = Ab + (size_t)(m0 + row) * K + kb;
  const unsigned short* pa1 = pa0 + (size_t)16 * K;
  const unsigned short* pb0 = Bb + (size_t)(n0 + row) * K + kb;
  const unsigned short* pb1 = pb0 + (size_t)16 * K;

  for (int k0 = 0; k0 < K; k0 += 32) {
    short8 a0 = *(const short8*)(pa0 + k0);
    short8 a1 = *(const short8*)(pa1 + k0);
    short8 b0 = *(const short8*)(pb0 + k0);
    short8 b1 = *(const short8*)(pb1 + k0);
    acc00 = __builtin_amdgcn_mfma_f32_16x16x32_bf16(a0, b0, acc00, 0, 0, 0);
    acc01 = __builtin_amdgcn_mfma_f32_16x16x32_bf16(a0, b1, acc01, 0, 0, 0);
    acc10 = __builtin_amdgcn_mfma_f32_16x16x32_bf16(a1, b0, acc10, 0, 0, 0);
    acc11 = __builtin_amdgcn_mfma_f32_16x16x32_bf16(a1, b1, acc11, 0, 0, 0);
  }

  f32x4 accs[2][2] = {{acc00, acc01}, {acc10, acc11}};
  #pragma unroll
  for (int i = 0; i < 2; ++i) {
    #pragma unroll
    for (int j = 0; j < 2; ++j) {
      int cn = n0 + 16 * j + (l & 15);
      float bv = bias ? bias[cn] : 0.f;
      #pragma unroll
      for (int r = 0; r < 4; ++r) {
        int cm = m0 + 16 * i + (l >> 4) * 4 + r;
        float v = accs[i][j][r] * scale + bv;
        if (ACT) v = 0.5f * v * (1.f + erff(v * 0.70710678118654752f));
        if (OUT == 0)      ((float*)Cp)[(size_t)cm * ldc + cn] = v;
        else               ((unsigned short*)Cp)[(size_t)cm * ldc + cn] = f2b(v);
      }
    }
  }
}

extern "C" void kernel_launch(void* const* d_in, const int* in_sizes, int n_in,
                              void* d_out, int out_size, void* d_ws, size_t ws_size,
                              hipStream_t stream)
{
  (void)n_in; (void)out_size; (void)ws_size;
  const float* x      = (const float*)d_in[0];
  const int*   batch  = (const int*)d_in[1];
  const float* w_attn = (const float*)d_in[3];
  // d_in[4] = b_attn: softmax shift-invariant, unused
  const float* Wq     = (const float*)d_in[5];
  const float* bq     = (const float*)d_in[6];
  const float* Wk     = (const float*)d_in[7];
  const float* bk     = (const float*)d_in[8];
  const float* W1     = (const float*)d_in[9];
  const float* b1     = (const float*)d_in[10];
  const float* W2     = (const float*)d_in[11];
  const float* b2     = (const float*)d_in[12];
  float* out = (float*)d_out;
  const int N = in_sizes[0] / DD;

  float* ws = (float*)d_ws;
  unsigned short* M_b = (unsigned short*)ws;          // 256x256 bf16 (32768 floats)
  float* bqk  = ws + 32768;                           // 256
  int*   offs = (int*)(ws + 32768 + 256);             // 2049 ints (pad 2304)
  float* base = ws + 32768 + 256 + 2304;
  unsigned short* u_b    = (unsigned short*)base;            // 2048*256 bf16
  unsigned short* comb_b = u_b + (size_t)GG * DD;            // 2048*1280
  unsigned short* h1_b   = comb_b + (size_t)GG * 1280;       // 2048*512
  unsigned short* Wq_b   = h1_b + (size_t)GG * 512;          // 65536
  unsigned short* Wk_b   = Wq_b + 65536;                     // 65536
  unsigned short* WkT_b  = Wk_b + 65536;                     // 65536
  unsigned short* W1T_b  = WkT_b + 65536;                    // 655360
  unsigned short* W2T_b  = W1T_b + 655360;                   // 131072

  k_prep<<<(983040 + 255) / 256, 256, 0, stream>>>(Wq, Wk, W1, W2, Wq_b, Wk_b, WkT_b, W1T_b, W2T_b);
  k_bqk<<<256, 64, 0, stream>>>(bq, Wk, bqk);
  k_offsets<<<(N + 255) / 256, 256, 0, stream>>>(batch, offs, N);
  // M = Wq @ Wk^T  (256x256, K=256), bf16 row-major M[a][c]
  gemm_mfma<0,1><<<dim3(4, 4), 256, 0, stream>>>(Wq_b, Wk_b, nullptr, M_b, 256, 256, 1.0f);
  // fused per-graph pooling (writes comb cols 0..1023 and u)
  k_fused<<<GG, 256, 0, stream>>>(x, offs, w_attn, M_b, bqk, u_b, comb_b);
  // h_s2s = u @ Wk + bk -> comb cols [1024,1280), bf16
  gemm_mfma<0,1><<<dim3(4, 32), 256, 0, stream>>>(u_b, WkT_b, bk, comb_b + 4 * DD, 256, 1280, 1.0f);
  // h1 = gelu(comb @ W1 + b1), bf16
  gemm_mfma<1,1><<<dim3(8, 32), 256, 0, stream>>>(comb_b, W1T_b, b1, h1_b, 1280, 512, 1.0f);
  // out = h1 @ W2 + b2, f32
  gemm_mfma<0,0><<<dim3(4, 32), 256, 0, stream>>>(h1_b, W2T_b, b2, out, 512, 256, 1.0f);
}